// Round 1
// baseline (430.051 us; speedup 1.0000x reference)
//
#include <hip/hip_runtime.h>

#define F 64  // DIN == DOUT == 64

// ---------------- h = x @ W ----------------
// Block: 256 threads, handles 64 rows. W staged in LDS (16 KB).
__global__ void gemm_kernel(const float* __restrict__ x, const float* __restrict__ W,
                            float* __restrict__ h, int n) {
    __shared__ float Ws[F * F];
    int tid = threadIdx.x;
    for (int i = tid; i < F * F; i += 256) Ws[i] = W[i];
    __syncthreads();
    int c = tid & 63;
    int rsub = tid >> 6;  // 0..3
    int base = blockIdx.x * 64;
    for (int rr = 0; rr < 64; rr += 4) {
        int r = base + rr + rsub;
        if (r < n) {
            const float* xr = x + (size_t)r * F;
            float acc = 0.f;
#pragma unroll
            for (int k = 0; k < F; ++k) acc += xr[k] * Ws[k * F + c];
            h[(size_t)r * F + c] = acc;
        }
    }
}

// ---------------- degree ----------------
__global__ void deg_init_kernel(float* __restrict__ deg, int n) {
    int i = blockIdx.x * blockDim.x + threadIdx.x;
    if (i < n) deg[i] = 1.0f;  // self-loop
}

__global__ void deg_count_kernel(const int* __restrict__ col, float* __restrict__ deg, int e) {
    int i = blockIdx.x * blockDim.x + threadIdx.x;
    if (i < e) atomicAdd(&deg[col[i]], 1.0f);
}

__global__ void dinv_kernel(const float* __restrict__ deg, float* __restrict__ dinv, int n) {
    int i = blockIdx.x * blockDim.x + threadIdx.x;
    if (i < n) dinv[i] = rsqrtf(deg[i]);  // deg >= 1 always (self-loop)
}

// ---------------- edge scatter ----------------
// One thread per (edge, channel). 64 consecutive threads share an edge, so
// h-gather and the atomics are coalesced 64-wide.
__global__ void scatter_kernel(const float* __restrict__ h, const int* __restrict__ row,
                               const int* __restrict__ col, const float* __restrict__ dinv,
                               float* __restrict__ out, int e) {
    long long gid = (long long)blockIdx.x * blockDim.x + threadIdx.x;
    int eidx = (int)(gid >> 6);
    if (eidx < e) {
        int c = (int)(gid & 63);
        int src = row[eidx];
        int dst = col[eidx];
        float nrm = dinv[src] * dinv[dst];
        atomicAdd(&out[(size_t)dst * F + c], nrm * h[(size_t)src * F + c]);
    }
}

// ---------------- finalize: self-loop + bias + relu ----------------
__global__ void finalize_kernel(const float* __restrict__ h, const float* __restrict__ dinv,
                                const float* __restrict__ b, float* __restrict__ out, int n) {
    int gid = blockIdx.x * blockDim.x + threadIdx.x;
    if (gid < n * F) {
        int i = gid >> 6;
        int c = gid & 63;
        float v = out[gid] + dinv[i] * dinv[i] * h[gid] + b[c];
        out[gid] = v > 0.f ? v : 0.f;
    }
}

extern "C" void kernel_launch(void* const* d_in, const int* in_sizes, int n_in,
                              void* d_out, int out_size, void* d_ws, size_t ws_size,
                              hipStream_t stream) {
    const float* x = (const float*)d_in[0];
    const int* ei  = (const int*)d_in[1];
    const float* W = (const float*)d_in[2];
    const float* b = (const float*)d_in[3];
    float* out = (float*)d_out;

    int n = in_sizes[0] / F;   // 100000
    int e = in_sizes[1] / 2;   // 1000000
    const int* row = ei;       // edge_index[0] = source
    const int* col = ei + e;   // edge_index[1] = target

    // workspace layout: h [n*64] | deg [n] | dinv [n]
    float* h    = (float*)d_ws;
    float* deg  = h + (size_t)n * F;
    float* dinv = deg + n;

    // 1. h = x @ W
    gemm_kernel<<<(n + 63) / 64, 256, 0, stream>>>(x, W, h, n);

    // 2. degree (on target index) + rsqrt
    deg_init_kernel<<<(n + 255) / 256, 256, 0, stream>>>(deg, n);
    deg_count_kernel<<<(e + 255) / 256, 256, 0, stream>>>(col, deg, e);
    dinv_kernel<<<(n + 255) / 256, 256, 0, stream>>>(deg, dinv, n);

    // 3. zero output accumulator (harness poisons it with 0xAA)
    hipMemsetAsync(d_out, 0, (size_t)n * F * sizeof(float), stream);

    // 4. edge scatter-add
    long long total = (long long)e * F;
    int sblocks = (int)((total + 255) / 256);
    scatter_kernel<<<sblocks, 256, 0, stream>>>(h, row, col, dinv, out, e);

    // 5. self-loop + bias + relu
    finalize_kernel<<<((n * F) + 255) / 256, 256, 0, stream>>>(h, dinv, b, out, n);
}

// Round 2
// 357.810 us; speedup vs baseline: 1.2019x; 1.2019x over previous
//
#include <hip/hip_runtime.h>

#define F 64  // DIN == DOUT == 64

// ---------------- h = x @ W ----------------
__global__ void gemm_kernel(const float* __restrict__ x, const float* __restrict__ W,
                            float* __restrict__ h, int n) {
    __shared__ float Ws[F * F];
    int tid = threadIdx.x;
    for (int i = tid; i < F * F; i += 256) Ws[i] = W[i];
    __syncthreads();
    int c = tid & 63;
    int rsub = tid >> 6;  // 0..3
    int base = blockIdx.x * 64;
    for (int rr = 0; rr < 64; rr += 4) {
        int r = base + rr + rsub;
        if (r < n) {
            const float* xr = x + (size_t)r * F;
            float acc = 0.f;
#pragma unroll
            for (int k = 0; k < F; ++k) acc += xr[k] * Ws[k * F + c];
            h[(size_t)r * F + c] = acc;
        }
    }
}

// ---------------- edge count on target ----------------
__global__ void cnt_kernel(const int* __restrict__ col, int* __restrict__ cnt, int e) {
    int i = blockIdx.x * blockDim.x + threadIdx.x;
    if (i < e) atomicAdd(&cnt[col[i]], 1);
}

__global__ void dinv_kernel(const int* __restrict__ cnt, float* __restrict__ dinv, int n) {
    int i = blockIdx.x * blockDim.x + threadIdx.x;
    if (i < n) dinv[i] = rsqrtf((float)(cnt[i] + 1));  // +1 self-loop
}

// ---------------- 3-kernel exclusive scan over cnt -> start ----------------
// S1: per-block (1024 items) exclusive scan into start, block total into bsum
__global__ void scan1_kernel(const int* __restrict__ cnt, int* __restrict__ start,
                             int* __restrict__ bsum, int n) {
    __shared__ int tmp[1024];
    int gid = blockIdx.x * 1024 + threadIdx.x;
    int v = (gid < n) ? cnt[gid] : 0;
    tmp[threadIdx.x] = v;
    __syncthreads();
    for (int off = 1; off < 1024; off <<= 1) {
        int t = (threadIdx.x >= off) ? tmp[threadIdx.x - off] : 0;
        __syncthreads();
        tmp[threadIdx.x] += t;
        __syncthreads();
    }
    if (gid < n) start[gid] = tmp[threadIdx.x] - v;  // exclusive
    if (threadIdx.x == 1023) bsum[blockIdx.x] = tmp[1023];
}

// S2: single-block exclusive scan of bsum (nb <= 1024)
__global__ void scan2_kernel(int* __restrict__ bsum, int nb) {
    __shared__ int tmp[1024];
    int v = (threadIdx.x < nb) ? bsum[threadIdx.x] : 0;
    tmp[threadIdx.x] = v;
    __syncthreads();
    for (int off = 1; off < 1024; off <<= 1) {
        int t = (threadIdx.x >= off) ? tmp[threadIdx.x - off] : 0;
        __syncthreads();
        tmp[threadIdx.x] += t;
        __syncthreads();
    }
    if (threadIdx.x < nb) bsum[threadIdx.x] = tmp[threadIdx.x] - v;  // exclusive
}

// S3: add block offset; init cursor = start
__global__ void scan3_kernel(int* __restrict__ start, int* __restrict__ cursor,
                             const int* __restrict__ bsum, int n) {
    int gid = blockIdx.x * 1024 + threadIdx.x;
    if (gid < n) {
        int s = start[gid] + bsum[blockIdx.x];
        start[gid] = s;
        cursor[gid] = s;
    }
}

// ---------------- bucket placement: CSR by destination ----------------
__global__ void place_kernel(const int* __restrict__ row, const int* __restrict__ col,
                             int* __restrict__ cursor, int* __restrict__ csr_src, int e) {
    int i = blockIdx.x * blockDim.x + threadIdx.x;
    if (i < e) {
        int p = atomicAdd(&cursor[col[i]], 1);
        csr_src[p] = row[i];
    }
}

// ---------------- gather: one wave per node, lane = channel ----------------
__global__ void gather_kernel(const float* __restrict__ h, const int* __restrict__ csr_src,
                              const int* __restrict__ start, const int* __restrict__ cnt,
                              const float* __restrict__ dinv, const float* __restrict__ b,
                              float* __restrict__ out, int n) {
    int gid = blockIdx.x * blockDim.x + threadIdx.x;
    int i = gid >> 6;    // node
    int c = gid & 63;    // channel
    if (i < n) {
        float di = dinv[i];
        float acc = di * h[(size_t)i * F + c];  // self-loop: dinv[i]*h[i][c]
        int s = start[i];
        int eend = s + cnt[i];
        for (int p = s; p < eend; ++p) {
            int src = csr_src[p];          // wave-uniform broadcast
            acc += dinv[src] * h[(size_t)src * F + c];
        }
        float v = di * acc + b[c];
        out[(size_t)i * F + c] = v > 0.f ? v : 0.f;
    }
}

extern "C" void kernel_launch(void* const* d_in, const int* in_sizes, int n_in,
                              void* d_out, int out_size, void* d_ws, size_t ws_size,
                              hipStream_t stream) {
    const float* x = (const float*)d_in[0];
    const int* ei  = (const int*)d_in[1];
    const float* W = (const float*)d_in[2];
    const float* b = (const float*)d_in[3];
    float* out = (float*)d_out;

    int n = in_sizes[0] / F;   // 100000
    int e = in_sizes[1] / 2;   // 1000000
    const int* row = ei;       // source
    const int* col = ei + e;   // target

    // workspace layout
    float* h     = (float*)d_ws;                    // n*64 floats
    int* cnt     = (int*)(h + (size_t)n * F);       // n
    float* dinv  = (float*)(cnt + n);               // n
    int* start   = (int*)(dinv + n);                // n
    int* cursor  = start + n;                       // n
    int* bsum    = cursor + n;                      // up to 1024
    int* csr_src = bsum + 1024;                     // e

    int nb = (n + 1023) / 1024;  // 98 scan blocks

    // 1. h = x @ W (independent of the CSR build)
    gemm_kernel<<<(n + 63) / 64, 256, 0, stream>>>(x, W, h, n);

    // 2. count edges per target
    hipMemsetAsync(cnt, 0, (size_t)n * sizeof(int), stream);
    cnt_kernel<<<(e + 255) / 256, 256, 0, stream>>>(col, cnt, e);

    // 3. dinv = rsqrt(cnt+1)
    dinv_kernel<<<(n + 255) / 256, 256, 0, stream>>>(cnt, dinv, n);

    // 4. exclusive scan -> start, cursor
    scan1_kernel<<<nb, 1024, 0, stream>>>(cnt, start, bsum, n);
    scan2_kernel<<<1, 1024, 0, stream>>>(bsum, nb);
    scan3_kernel<<<nb, 1024, 0, stream>>>(start, cursor, bsum, n);

    // 5. bucket placement
    place_kernel<<<(e + 255) / 256, 256, 0, stream>>>(row, col, cursor, csr_src, e);

    // 6. gather + self-loop + bias + relu (writes every out element)
    gather_kernel<<<((size_t)n * F + 255) / 256, 256, 0, stream>>>(
        h, csr_src, start, cnt, dinv, b, out, n);
}

// Round 3
// 256.766 us; speedup vs baseline: 1.6749x; 1.3935x over previous
//
#include <hip/hip_runtime.h>
#include <hip/hip_bf16.h>

#define F 64  // DIN == DOUT == 64

// ---------------- h = x @ W  (output bf16) ----------------
// 256 threads/block, 64 rows/block. W staged in LDS. Each thread keeps 4
// accumulators (4 rows) so one LDS read feeds 4 FMAs; x-row pointers are
// wave-uniform (readfirstlane) so the k-loop x reads become s_loads.
__global__ void gemm_kernel(const float* __restrict__ x, const float* __restrict__ W,
                            __hip_bfloat16* __restrict__ h, int n) {
    __shared__ float Ws[F * F];
    int tid = threadIdx.x;
    for (int i = tid; i < F * F; i += 256) Ws[i] = W[i];
    __syncthreads();
    int c = tid & 63;
    int wv = __builtin_amdgcn_readfirstlane(tid >> 6);  // wave id 0..3
    int base = blockIdx.x * 64 + wv * 16;
    for (int it = 0; it < 4; ++it) {
        int r0 = base + it * 4;
        if (r0 + 3 < n) {
            const float* x0 = x + (size_t)r0 * F;
            float a0 = 0.f, a1 = 0.f, a2 = 0.f, a3 = 0.f;
#pragma unroll
            for (int k = 0; k < F; ++k) {
                float w = Ws[k * F + c];
                a0 += x0[k] * w;
                a1 += x0[F + k] * w;
                a2 += x0[2 * F + k] * w;
                a3 += x0[3 * F + k] * w;
            }
            h[(size_t)r0 * F + c]       = __float2bfloat16(a0);
            h[(size_t)(r0 + 1) * F + c] = __float2bfloat16(a1);
            h[(size_t)(r0 + 2) * F + c] = __float2bfloat16(a2);
            h[(size_t)(r0 + 3) * F + c] = __float2bfloat16(a3);
        } else {
            for (int j = 0; j < 4; ++j) {
                int r = r0 + j;
                if (r < n) {
                    const float* xr = x + (size_t)r * F;
                    float acc = 0.f;
#pragma unroll
                    for (int k = 0; k < F; ++k) acc += xr[k] * Ws[k * F + c];
                    h[(size_t)r * F + c] = __float2bfloat16(acc);
                }
            }
        }
    }
}

// ---------------- edge count on target (4 edges/thread) ----------------
__global__ void cnt_kernel(const int* __restrict__ col, int* __restrict__ cnt, int e) {
    int i4 = (blockIdx.x * blockDim.x + threadIdx.x) * 4;
    if (i4 + 3 < e) {
        int4 cs = *(const int4*)(col + i4);
        atomicAdd(&cnt[cs.x], 1);
        atomicAdd(&cnt[cs.y], 1);
        atomicAdd(&cnt[cs.z], 1);
        atomicAdd(&cnt[cs.w], 1);
    } else {
        for (int i = i4; i < e; ++i) atomicAdd(&cnt[col[i]], 1);
    }
}

// ---------------- scan1: per-block exclusive scan + fused dinv ----------------
__global__ void scan1_kernel(const int* __restrict__ cnt, int* __restrict__ start,
                             int* __restrict__ bsum, float* __restrict__ dinv, int n) {
    __shared__ int tmp[1024];
    int gid = blockIdx.x * 1024 + threadIdx.x;
    int v = (gid < n) ? cnt[gid] : 0;
    if (gid < n) dinv[gid] = rsqrtf((float)(v + 1));  // +1 self-loop
    tmp[threadIdx.x] = v;
    __syncthreads();
    for (int off = 1; off < 1024; off <<= 1) {
        int t = (threadIdx.x >= off) ? tmp[threadIdx.x - off] : 0;
        __syncthreads();
        tmp[threadIdx.x] += t;
        __syncthreads();
    }
    if (gid < n) start[gid] = tmp[threadIdx.x] - v;  // exclusive
    if (threadIdx.x == 1023) bsum[blockIdx.x] = tmp[1023];
}

__global__ void scan2_kernel(int* __restrict__ bsum, int nb) {
    __shared__ int tmp[1024];
    int v = (threadIdx.x < nb) ? bsum[threadIdx.x] : 0;
    tmp[threadIdx.x] = v;
    __syncthreads();
    for (int off = 1; off < 1024; off <<= 1) {
        int t = (threadIdx.x >= off) ? tmp[threadIdx.x - off] : 0;
        __syncthreads();
        tmp[threadIdx.x] += t;
        __syncthreads();
    }
    if (threadIdx.x < nb) bsum[threadIdx.x] = tmp[threadIdx.x] - v;
}

__global__ void scan3_kernel(int* __restrict__ start, int* __restrict__ cursor,
                             const int* __restrict__ bsum, int n) {
    int gid = blockIdx.x * 1024 + threadIdx.x;
    if (gid < n) {
        int s = start[gid] + bsum[blockIdx.x];
        start[gid] = s;
        cursor[gid] = s;
    }
}

// ---------------- bucket placement: (src, dinv[src]) pairs ----------------
__global__ void place_kernel(const int* __restrict__ row, const int* __restrict__ col,
                             const float* __restrict__ dinv, int* __restrict__ cursor,
                             int2* __restrict__ csr, int e) {
    int i4 = (blockIdx.x * blockDim.x + threadIdx.x) * 4;
    if (i4 + 3 < e) {
        int4 rs = *(const int4*)(row + i4);
        int4 cs = *(const int4*)(col + i4);
        int p0 = atomicAdd(&cursor[cs.x], 1);
        int p1 = atomicAdd(&cursor[cs.y], 1);
        int p2 = atomicAdd(&cursor[cs.z], 1);
        int p3 = atomicAdd(&cursor[cs.w], 1);
        csr[p0] = make_int2(rs.x, __float_as_int(dinv[rs.x]));
        csr[p1] = make_int2(rs.y, __float_as_int(dinv[rs.y]));
        csr[p2] = make_int2(rs.z, __float_as_int(dinv[rs.z]));
        csr[p3] = make_int2(rs.w, __float_as_int(dinv[rs.w]));
    } else {
        for (int i = i4; i < e; ++i) {
            int p = atomicAdd(&cursor[col[i]], 1);
            csr[p] = make_int2(row[i], __float_as_int(dinv[row[i]]));
        }
    }
}

// ---------------- gather: one wave per node, lane = channel ----------------
// cursor[i] == start[i] + cnt[i] after place, so it serves as the end pointer.
__global__ void gather_kernel(const __hip_bfloat16* __restrict__ h,
                              const int2* __restrict__ csr,
                              const int* __restrict__ start, const int* __restrict__ cursor,
                              const float* __restrict__ dinv, const float* __restrict__ b,
                              float* __restrict__ out, int n) {
    int gid = blockIdx.x * blockDim.x + threadIdx.x;
    int i = gid >> 6;
    int c = gid & 63;
    if (i >= n) return;
    float di = dinv[i];
    float acc = di * __bfloat162float(h[(size_t)i * F + c]);  // self-loop
    int p = start[i];
    int pend = cursor[i];
    for (; p + 4 <= pend; p += 4) {
        int2 e0 = csr[p];
        int2 e1 = csr[p + 1];
        int2 e2 = csr[p + 2];
        int2 e3 = csr[p + 3];
        float h0 = __bfloat162float(h[(size_t)e0.x * F + c]);
        float h1 = __bfloat162float(h[(size_t)e1.x * F + c]);
        float h2 = __bfloat162float(h[(size_t)e2.x * F + c]);
        float h3 = __bfloat162float(h[(size_t)e3.x * F + c]);
        acc += __int_as_float(e0.y) * h0;
        acc += __int_as_float(e1.y) * h1;
        acc += __int_as_float(e2.y) * h2;
        acc += __int_as_float(e3.y) * h3;
    }
    for (; p < pend; ++p) {
        int2 ee = csr[p];
        acc += __int_as_float(ee.y) * __bfloat162float(h[(size_t)ee.x * F + c]);
    }
    float v = di * acc + b[c];
    out[(size_t)i * F + c] = v > 0.f ? v : 0.f;
}

extern "C" void kernel_launch(void* const* d_in, const int* in_sizes, int n_in,
                              void* d_out, int out_size, void* d_ws, size_t ws_size,
                              hipStream_t stream) {
    const float* x = (const float*)d_in[0];
    const int* ei  = (const int*)d_in[1];
    const float* W = (const float*)d_in[2];
    const float* b = (const float*)d_in[3];
    float* out = (float*)d_out;

    int n = in_sizes[0] / F;   // 100000
    int e = in_sizes[1] / 2;   // 1000000
    const int* row = ei;       // source
    const int* col = ei + e;   // target

    // workspace layout (8B-aligned pieces first)
    __hip_bfloat16* h = (__hip_bfloat16*)d_ws;              // n*F bf16 (12.8 MB)
    int2* csr    = (int2*)((char*)d_ws + (size_t)n * F * 2); // e pairs (8 MB)
    int* cnt     = (int*)(csr + e);                          // n
    float* dinv  = (float*)(cnt + n);                        // n
    int* start   = (int*)(dinv + n);                         // n
    int* cursor  = start + n;                                // n
    int* bsum    = cursor + n;                               // <=1024

    int nb = (n + 1023) / 1024;  // 98

    // 1. h = x @ W (bf16 output)
    gemm_kernel<<<(n + 63) / 64, 256, 0, stream>>>(x, W, h, n);

    // 2. count edges per target
    hipMemsetAsync(cnt, 0, (size_t)n * sizeof(int), stream);
    cnt_kernel<<<(e / 4 + 255) / 256, 256, 0, stream>>>(col, cnt, e);

    // 3. exclusive scan (+ dinv fused into pass 1)
    scan1_kernel<<<nb, 1024, 0, stream>>>(cnt, start, bsum, dinv, n);
    scan2_kernel<<<1, 1024, 0, stream>>>(bsum, nb);
    scan3_kernel<<<nb, 1024, 0, stream>>>(start, cursor, bsum, n);

    // 4. bucket placement with precomputed edge weight
    place_kernel<<<(e / 4 + 255) / 256, 256, 0, stream>>>(row, col, dinv, cursor, csr, e);

    // 5. gather + self-loop + bias + relu
    gather_kernel<<<((size_t)n * F + 255) / 256, 256, 0, stream>>>(
        h, csr, start, cursor, dinv, b, out, n);
}